// Round 1
// baseline (257.437 us; speedup 1.0000x reference)
//
#include <hip/hip_runtime.h>
#include <hip/hip_bf16.h>

// Problem constants: B=64, T=N=1024, d=64, k=128.

typedef __attribute__((ext_vector_type(8))) short bfrag;   // 8 x bf16 (4 VGPRs)
typedef __attribute__((ext_vector_type(4))) float ffrag;   // 4 x f32 acc

__device__ __forceinline__ unsigned short f2b(float f) {
  unsigned u = __builtin_bit_cast(unsigned, f);
  u += 0x7FFFu + ((u >> 16) & 1u);          // RNE f32 -> bf16 (finite inputs)
  return (unsigned short)(u >> 16);
}
__device__ __forceinline__ float b2f(unsigned short h) {
  return __builtin_bit_cast(float, (unsigned)h << 16);
}
__device__ __forceinline__ float ftanh(float x) {
  // tanh(x) = 1 - 2/(e^{2x}+1); |err| ~1e-6 absolute, fine vs 5.7e-3 threshold
  float e = __expf(x + x);
  return 1.0f - 2.0f * __builtin_amdgcn_rcpf(e + 1.0f);
}

#define MFMA(a, b, c) __builtin_amdgcn_mfma_f32_16x16x32_bf16((a), (b), (c), 0, 0, 0)

// ---------------------------------------------------------------------------
// prep: RWb = bf16(review@Wl)  [B,T,64]
//       Rb  = bf16(Wr@review^T) stored [B,128,T]
//       Pb  = bf16(Wp@post^T)   stored [B,128,N]
//       postb = bf16(post)      [B,N,64]
// grid (8 chunks, 64 b, 2 sides), 256 threads
// ---------------------------------------------------------------------------
__global__ __launch_bounds__(256) void prep_kernel(
    const float* __restrict__ review, const float* __restrict__ post,
    const float* __restrict__ Wl, const float* __restrict__ Wr,
    const float* __restrict__ Wp,
    unsigned short* __restrict__ RWb, unsigned short* __restrict__ Rb,
    unsigned short* __restrict__ Pb, unsigned short* __restrict__ postb)
{
  const int chunk = blockIdx.x, b = blockIdx.y, side = blockIdx.z;
  const int tid = threadIdx.x, lane = tid & 63, w = tid >> 6;
  const int lr = lane & 15, lg = lane >> 4;
  const int r0 = chunk * 128;

  __shared__ __align__(16) unsigned short seqs[128][72];  // seq rows [r][d]
  __shared__ __align__(16) unsigned short wgt[128][72];   // Wr or Wp [k][d]
  __shared__ __align__(16) unsigned short wlt[64][72];    // Wl^T [i][d]

  const float* seq = (side == 0) ? review : post;
  for (int i = tid; i < 128 * 64; i += 256) {
    int r = i >> 6, d = i & 63;
    unsigned short h = f2b(seq[((size_t)(b * 1024 + r0 + r)) * 64 + d]);
    seqs[r][d] = h;
    if (side == 1) postb[((size_t)(b * 1024 + r0 + r)) * 64 + d] = h;
  }
  const float* wkd = (side == 0) ? Wr : Wp;
  for (int i = tid; i < 128 * 64; i += 256) {
    int k = i >> 6, d = i & 63;
    wgt[k][d] = f2b(wkd[k * 64 + d]);
  }
  if (side == 0) {
    for (int i = tid; i < 64 * 64; i += 256) {
      int d = i >> 6, c = i & 63;
      wlt[c][d] = f2b(Wl[d * 64 + c]);
    }
  }
  __syncthreads();

  if (side == 0) {
    // RW = seqs @ Wl : [128 x 64]; wave w owns t in [32w, 32w+32)
    ffrag acc[2][4] = {};
#pragma unroll
    for (int ks = 0; ks < 2; ++ks)
#pragma unroll
      for (int ts = 0; ts < 2; ++ts) {
        bfrag a = *(const bfrag*)&seqs[w * 32 + ts * 16 + lr][ks * 32 + lg * 8];
#pragma unroll
        for (int is = 0; is < 4; ++is) {
          bfrag bb = *(const bfrag*)&wlt[is * 16 + lr][ks * 32 + lg * 8];
          acc[ts][is] = MFMA(a, bb, acc[ts][is]);
        }
      }
#pragma unroll
    for (int ts = 0; ts < 2; ++ts)
#pragma unroll
      for (int is = 0; is < 4; ++is)
#pragma unroll
        for (int j = 0; j < 4; ++j) {
          int t = r0 + w * 32 + ts * 16 + lg * 4 + j;
          int i2 = is * 16 + lr;
          RWb[((size_t)(b * 1024 + t)) * 64 + i2] = f2b(acc[ts][is][j]);
        }
  }
  {
    // R/P = wgt @ seqs^T : [128 k x 128 r]; wave w owns k in [32w, 32w+32)
    ffrag acc[2][8] = {};
#pragma unroll
    for (int ks = 0; ks < 2; ++ks)
#pragma unroll
      for (int ksb = 0; ksb < 2; ++ksb) {
        bfrag a = *(const bfrag*)&wgt[w * 32 + ksb * 16 + lr][ks * 32 + lg * 8];
#pragma unroll
        for (int ts = 0; ts < 8; ++ts) {
          bfrag bb = *(const bfrag*)&seqs[ts * 16 + lr][ks * 32 + lg * 8];
          acc[ksb][ts] = MFMA(a, bb, acc[ksb][ts]);
        }
      }
    unsigned short* dst = (side == 0) ? Rb : Pb;
#pragma unroll
    for (int ksb = 0; ksb < 2; ++ksb)
#pragma unroll
      for (int ts = 0; ts < 8; ++ts)
#pragma unroll
        for (int j = 0; j < 4; ++j) {
          int k = w * 32 + ksb * 16 + lg * 4 + j;
          int t = r0 + ts * 16 + lr;
          dst[((size_t)(b * 128 + k)) * 1024 + t] = f2b(acc[ksb][ts][j]);
        }
  }
}

// ---------------------------------------------------------------------------
// hp: per block (n-strip of 128, batch b): loop t-chunks of 32,
//     Ltile = tanh(RW@post^T) -> LDS [n][t]; Hp_acc[k,n] += R[k,t]@L[t,n];
//     epilogue Hp = tanh(P + acc), z_p[n] = sum_k whp[k]*Hp  (all k in block)
// ---------------------------------------------------------------------------
__global__ __launch_bounds__(256) void hp_kernel(
    const unsigned short* __restrict__ RWb, const unsigned short* __restrict__ Rb,
    const unsigned short* __restrict__ Pb, const unsigned short* __restrict__ postb,
    const float* __restrict__ whp, float* __restrict__ zp)
{
  const int n0 = blockIdx.x * 128, b = blockIdx.y;
  const int tid = threadIdx.x, lane = tid & 63, w = tid >> 6;
  const int lr = lane & 15, lg = lane >> 4;

  __shared__ __align__(16) unsigned short postl[128][72]; // post strip [n][d]
  __shared__ __align__(16) unsigned short rwl[32][72];    // RW chunk [t][d]
  __shared__ __align__(16) unsigned short rl[128][40];    // R chunk [k][t]
  __shared__ __align__(16) unsigned short ll[128][40];    // L^T tile [n][t]
  __shared__ float whps[128];
  __shared__ float zacc[4][128];

  if (tid < 128) whps[tid] = whp[tid];
  const unsigned* pg = (const unsigned*)(postb + ((size_t)(b * 1024 + n0)) * 64);
  for (int i = tid; i < 128 * 32; i += 256) {
    int r = i >> 5, p = i & 31;
    *(unsigned*)&postl[r][p * 2] = pg[i];
  }
  __syncthreads();

  ffrag acc[2][8] = {};   // [ksub][nsub]: k in [32w,32w+32), n all 128
  for (int tc = 0; tc < 32; ++tc) {
    const int t0 = tc * 32;
    const unsigned* rg = (const unsigned*)(RWb + ((size_t)(b * 1024 + t0)) * 64);
    for (int i = tid; i < 1024; i += 256) {
      int r = i >> 5, p = i & 31;
      *(unsigned*)&rwl[r][p * 2] = rg[i];
    }
    const unsigned* rb = (const unsigned*)Rb + (size_t)(b * 128) * 512 + t0 / 2;
    for (int i = tid; i < 2048; i += 256) {
      int k = i >> 4, p = i & 15;
      *(unsigned*)&rl[k][p * 2] = rb[(size_t)k * 512 + p];
    }
    __syncthreads();

    // Ltile [32t x 32n per wave], wave w owns n in [32w, 32w+32)
    ffrag la[2][2] = {};
#pragma unroll
    for (int ks = 0; ks < 2; ++ks)
#pragma unroll
      for (int ts = 0; ts < 2; ++ts) {
        bfrag a = *(const bfrag*)&rwl[ts * 16 + lr][ks * 32 + lg * 8];
#pragma unroll
        for (int ns = 0; ns < 2; ++ns) {
          bfrag bb = *(const bfrag*)&postl[w * 32 + ns * 16 + lr][ks * 32 + lg * 8];
          la[ts][ns] = MFMA(a, bb, la[ts][ns]);
        }
      }
#pragma unroll
    for (int ts = 0; ts < 2; ++ts)
#pragma unroll
      for (int ns = 0; ns < 2; ++ns) {
        int n = w * 32 + ns * 16 + lr;
        int tt = ts * 16 + lg * 4;
        unsigned p0 = ((unsigned)f2b(ftanh(la[ts][ns][1])) << 16) | f2b(ftanh(la[ts][ns][0]));
        unsigned p1 = ((unsigned)f2b(ftanh(la[ts][ns][3])) << 16) | f2b(ftanh(la[ts][ns][2]));
        uint2 pk; pk.x = p0; pk.y = p1;
        *(uint2*)&ll[n][tt] = pk;   // 8B store, 8-aligned
      }
    __syncthreads();

    // Hp GEMM: K = 32 (the t-chunk)
#pragma unroll
    for (int ksb = 0; ksb < 2; ++ksb) {
      bfrag a = *(const bfrag*)&rl[w * 32 + ksb * 16 + lr][lg * 8];
#pragma unroll
      for (int ns = 0; ns < 8; ++ns) {
        bfrag bb = *(const bfrag*)&ll[ns * 16 + lr][lg * 8];
        acc[ksb][ns] = MFMA(a, bb, acc[ksb][ns]);
      }
    }
    __syncthreads();
  }

  float zpart[8] = {0, 0, 0, 0, 0, 0, 0, 0};
#pragma unroll
  for (int ksb = 0; ksb < 2; ++ksb)
#pragma unroll
    for (int ns = 0; ns < 8; ++ns)
#pragma unroll
      for (int j = 0; j < 4; ++j) {
        int k = w * 32 + ksb * 16 + lg * 4 + j;
        int n = ns * 16 + lr;
        float pt = b2f(Pb[((size_t)(b * 128 + k)) * 1024 + n0 + n]);
        float h = ftanh(acc[ksb][ns][j] + pt);
        zpart[ns] += whps[k] * h;
      }
#pragma unroll
  for (int ns = 0; ns < 8; ++ns) {
    zpart[ns] += __shfl_xor(zpart[ns], 16);
    zpart[ns] += __shfl_xor(zpart[ns], 32);
  }
  if (lg == 0) {
#pragma unroll
    for (int ns = 0; ns < 8; ++ns) zacc[w][ns * 16 + lr] = zpart[ns];
  }
  __syncthreads();
  if (tid < 128)
    zp[(size_t)b * 1024 + n0 + tid] =
        zacc[0][tid] + zacc[1][tid] + zacc[2][tid] + zacc[3][tid];
}

// ---------------------------------------------------------------------------
// hr: symmetric: per block (t-strip of 128, b): loop n-chunks of 32,
//     Ltile -> LDS [t][n]; Hr_acc[k,t] += P[k,n]@L^T[n,t];
//     epilogue Hr = tanh(R + acc), z_r[t] = sum_k whr[k]*Hr
// ---------------------------------------------------------------------------
__global__ __launch_bounds__(256) void hr_kernel(
    const unsigned short* __restrict__ RWb, const unsigned short* __restrict__ Rb,
    const unsigned short* __restrict__ Pb, const unsigned short* __restrict__ postb,
    const float* __restrict__ whr, float* __restrict__ zr)
{
  const int t0s = blockIdx.x * 128, b = blockIdx.y;
  const int tid = threadIdx.x, lane = tid & 63, w = tid >> 6;
  const int lr = lane & 15, lg = lane >> 4;

  __shared__ __align__(16) unsigned short rws[128][72];   // RW strip [t][d]
  __shared__ __align__(16) unsigned short postc[32][72];  // post chunk [n][d]
  __shared__ __align__(16) unsigned short pl[128][40];    // P chunk [k][n]
  __shared__ __align__(16) unsigned short ll[128][40];    // L tile [t][n]
  __shared__ float whrs[128];
  __shared__ float zacc[4][128];

  if (tid < 128) whrs[tid] = whr[tid];
  const unsigned* rg = (const unsigned*)(RWb + ((size_t)(b * 1024 + t0s)) * 64);
  for (int i = tid; i < 128 * 32; i += 256) {
    int r = i >> 5, p = i & 31;
    *(unsigned*)&rws[r][p * 2] = rg[i];
  }
  __syncthreads();

  ffrag acc[2][8] = {};   // [ksub][tsub]
  for (int nc = 0; nc < 32; ++nc) {
    const int n0 = nc * 32;
    const unsigned* pg = (const unsigned*)(postb + ((size_t)(b * 1024 + n0)) * 64);
    for (int i = tid; i < 1024; i += 256) {
      int r = i >> 5, p = i & 31;
      *(unsigned*)&postc[r][p * 2] = pg[i];
    }
    const unsigned* pb = (const unsigned*)Pb + (size_t)(b * 128) * 512 + n0 / 2;
    for (int i = tid; i < 2048; i += 256) {
      int k = i >> 4, p = i & 15;
      *(unsigned*)&pl[k][p * 2] = pb[(size_t)k * 512 + p];
    }
    __syncthreads();

    // Ltile [32t per wave x 32n], wave w owns t in [32w, 32w+32)
    ffrag la[2][2] = {};
#pragma unroll
    for (int ks = 0; ks < 2; ++ks)
#pragma unroll
      for (int ts = 0; ts < 2; ++ts) {
        bfrag a = *(const bfrag*)&rws[w * 32 + ts * 16 + lr][ks * 32 + lg * 8];
#pragma unroll
        for (int ns = 0; ns < 2; ++ns) {
          bfrag bb = *(const bfrag*)&postc[ns * 16 + lr][ks * 32 + lg * 8];
          la[ts][ns] = MFMA(a, bb, la[ts][ns]);
        }
      }
#pragma unroll
    for (int ts = 0; ts < 2; ++ts)
#pragma unroll
      for (int ns = 0; ns < 2; ++ns)
#pragma unroll
        for (int j = 0; j < 4; ++j) {
          int t = w * 32 + ts * 16 + lg * 4 + j;
          int n = ns * 16 + lr;
          ll[t][n] = f2b(ftanh(la[ts][ns][j]));
        }
    __syncthreads();

    // Hr GEMM: K = 32 (the n-chunk)
#pragma unroll
    for (int ksb = 0; ksb < 2; ++ksb) {
      bfrag a = *(const bfrag*)&pl[w * 32 + ksb * 16 + lr][lg * 8];
#pragma unroll
      for (int ts = 0; ts < 8; ++ts) {
        bfrag bb = *(const bfrag*)&ll[ts * 16 + lr][lg * 8];
        acc[ksb][ts] = MFMA(a, bb, acc[ksb][ts]);
      }
    }
    __syncthreads();
  }

  float zpart[8] = {0, 0, 0, 0, 0, 0, 0, 0};
#pragma unroll
  for (int ksb = 0; ksb < 2; ++ksb)
#pragma unroll
    for (int ts = 0; ts < 8; ++ts)
#pragma unroll
      for (int j = 0; j < 4; ++j) {
        int k = w * 32 + ksb * 16 + lg * 4 + j;
        int t = ts * 16 + lr;
        float rt = b2f(Rb[((size_t)(b * 128 + k)) * 1024 + t0s + t]);
        float h = ftanh(acc[ksb][ts][j] + rt);
        zpart[ts] += whrs[k] * h;
      }
#pragma unroll
  for (int ts = 0; ts < 8; ++ts) {
    zpart[ts] += __shfl_xor(zpart[ts], 16);
    zpart[ts] += __shfl_xor(zpart[ts], 32);
  }
  if (lg == 0) {
#pragma unroll
    for (int ts = 0; ts < 8; ++ts) zacc[w][ts * 16 + lr] = zpart[ts];
  }
  __syncthreads();
  if (tid < 128)
    zr[(size_t)b * 1024 + t0s + tid] =
        zacc[0][tid] + zacc[1][tid] + zacc[2][tid] + zacc[3][tid];
}

// ---------------------------------------------------------------------------
// final: per b: softmax(z) -> weighted sum of f32 sequences -> out [B,128]
// ---------------------------------------------------------------------------
__global__ __launch_bounds__(256) void final_kernel(
    const float* __restrict__ review, const float* __restrict__ post,
    const float* __restrict__ zp, const float* __restrict__ zr,
    float* __restrict__ out)
{
  const int b = blockIdx.x, tid = threadIdx.x;
  __shared__ float zl[1024];
  __shared__ float red[256];
  __shared__ float cacc[4][64];

  for (int side = 0; side < 2; ++side) {
    const float* z = (side == 0) ? zp : zr;
    const float* seq = (side == 0) ? post : review;
    for (int i = tid; i < 1024; i += 256) zl[i] = z[(size_t)b * 1024 + i];
    __syncthreads();
    float m = -3.4e38f;
    for (int i = tid; i < 1024; i += 256) m = fmaxf(m, zl[i]);
    red[tid] = m;
    __syncthreads();
    for (int s = 128; s > 0; s >>= 1) {
      if (tid < s) red[tid] = fmaxf(red[tid], red[tid + s]);
      __syncthreads();
    }
    m = red[0];
    __syncthreads();
    float sm = 0.f;
    for (int i = tid; i < 1024; i += 256) {
      float e = __expf(zl[i] - m);
      zl[i] = e;
      sm += e;
    }
    red[tid] = sm;
    __syncthreads();
    for (int s = 128; s > 0; s >>= 1) {
      if (tid < s) red[tid] += red[tid + s];
      __syncthreads();
    }
    float inv = 1.0f / red[0];
    __syncthreads();
    const int d = tid & 63, g = tid >> 6;
    float a = 0.f;
    for (int n = g * 256; n < g * 256 + 256; ++n)
      a += zl[n] * seq[((size_t)(b * 1024 + n)) * 64 + d];
    cacc[g][d] = a * inv;
    __syncthreads();
    if (tid < 64)
      out[b * 128 + side * 64 + tid] =
          cacc[0][tid] + cacc[1][tid] + cacc[2][tid] + cacc[3][tid];
    __syncthreads();
  }
}

// ---------------------------------------------------------------------------
extern "C" void kernel_launch(void* const* d_in, const int* in_sizes, int n_in,
                              void* d_out, int out_size, void* d_ws, size_t ws_size,
                              hipStream_t stream) {
  const float* review = (const float*)d_in[0];
  const float* post   = (const float*)d_in[1];
  const float* Wl     = (const float*)d_in[2];
  const float* Wr     = (const float*)d_in[3];
  const float* Wp     = (const float*)d_in[4];
  const float* whr    = (const float*)d_in[5];
  const float* whp    = (const float*)d_in[6];
  float* out = (float*)d_out;

  char* ws = (char*)d_ws;
  // Workspace layout (50.9 MB total):
  unsigned short* RWb   = (unsigned short*)(ws);                        //  8 MiB
  unsigned short* Rb    = (unsigned short*)(ws + (size_t)8  * 1048576); // 16 MiB
  unsigned short* Pb    = (unsigned short*)(ws + (size_t)24 * 1048576); // 16 MiB
  unsigned short* postb = (unsigned short*)(ws + (size_t)40 * 1048576); //  8 MiB
  float* zp = (float*)(ws + (size_t)48 * 1048576);                      // 256 KiB
  float* zr = (float*)(ws + (size_t)48 * 1048576 + 262144);             // 256 KiB

  prep_kernel<<<dim3(8, 64, 2), dim3(256), 0, stream>>>(
      review, post, Wl, Wr, Wp, RWb, Rb, Pb, postb);
  hp_kernel<<<dim3(8, 64), dim3(256), 0, stream>>>(
      RWb, Rb, Pb, postb, whp, zp);
  hr_kernel<<<dim3(8, 64), dim3(256), 0, stream>>>(
      RWb, Rb, Pb, postb, whr, zr);
  final_kernel<<<dim3(64), dim3(256), 0, stream>>>(
      review, post, zp, zr, out);
}

// Round 2
// 129.348 us; speedup vs baseline: 1.9903x; 1.9903x over previous
//
#include <hip/hip_runtime.h>
#include <hip/hip_bf16.h>

// Problem constants: B=64, T=N=1024, d=64, k=128.

typedef __attribute__((ext_vector_type(8))) short bfrag;   // 8 x bf16 (4 VGPRs)
typedef __attribute__((ext_vector_type(4))) float ffrag;   // 4 x f32 acc

__device__ __forceinline__ unsigned short f2b(float f) {
  unsigned u = __builtin_bit_cast(unsigned, f);
  u += 0x7FFFu + ((u >> 16) & 1u);          // RNE f32 -> bf16 (finite inputs)
  return (unsigned short)(u >> 16);
}
__device__ __forceinline__ float b2f(unsigned short h) {
  return __builtin_bit_cast(float, (unsigned)h << 16);
}
__device__ __forceinline__ float ftanh(float x) {
  // tanh(x) = 1 - 2/(e^{2x}+1); |err| ~1e-6 absolute, fine vs 5.7e-3 threshold
  float e = __expf(x + x);
  return 1.0f - 2.0f * __builtin_amdgcn_rcpf(e + 1.0f);
}

#define MFMA(a, b, c) __builtin_amdgcn_mfma_f32_16x16x32_bf16((a), (b), (c), 0, 0, 0)

// ---------------------------------------------------------------------------
// prep: RWb = bf16(review@Wl)  [B,T,64]
//       Rb  = bf16(Wr@review^T) stored [B,128,T]
//       Pb  = bf16(Wp@post^T)   stored [B,128,N]
//       postb = bf16(post)      [B,N,64]
// grid (8 chunks, 64 b, 2 sides), 256 threads
// ---------------------------------------------------------------------------
__global__ __launch_bounds__(256) void prep_kernel(
    const float* __restrict__ review, const float* __restrict__ post,
    const float* __restrict__ Wl, const float* __restrict__ Wr,
    const float* __restrict__ Wp,
    unsigned short* __restrict__ RWb, unsigned short* __restrict__ Rb,
    unsigned short* __restrict__ Pb, unsigned short* __restrict__ postb)
{
  const int chunk = blockIdx.x, b = blockIdx.y, side = blockIdx.z;
  const int tid = threadIdx.x, lane = tid & 63, w = tid >> 6;
  const int lr = lane & 15, lg = lane >> 4;
  const int r0 = chunk * 128;

  __shared__ __align__(16) unsigned short seqs[128][72];  // seq rows [r][d]
  __shared__ __align__(16) unsigned short wgt[128][72];   // Wr or Wp [k][d]
  __shared__ __align__(16) unsigned short wlt[64][72];    // Wl^T [i][d]

  const float* seq = (side == 0) ? review : post;
  for (int i = tid; i < 128 * 64; i += 256) {
    int r = i >> 6, d = i & 63;
    unsigned short h = f2b(seq[((size_t)(b * 1024 + r0 + r)) * 64 + d]);
    seqs[r][d] = h;
    if (side == 1) postb[((size_t)(b * 1024 + r0 + r)) * 64 + d] = h;
  }
  const float* wkd = (side == 0) ? Wr : Wp;
  for (int i = tid; i < 128 * 64; i += 256) {
    int k = i >> 6, d = i & 63;
    wgt[k][d] = f2b(wkd[k * 64 + d]);
  }
  if (side == 0) {
    for (int i = tid; i < 64 * 64; i += 256) {
      int d = i >> 6, c = i & 63;
      wlt[c][d] = f2b(Wl[d * 64 + c]);
    }
  }
  __syncthreads();

  if (side == 0) {
    // RW = seqs @ Wl : [128 x 64]; wave w owns t in [32w, 32w+32)
    ffrag acc[2][4] = {};
#pragma unroll
    for (int ks = 0; ks < 2; ++ks)
#pragma unroll
      for (int ts = 0; ts < 2; ++ts) {
        bfrag a = *(const bfrag*)&seqs[w * 32 + ts * 16 + lr][ks * 32 + lg * 8];
#pragma unroll
        for (int is = 0; is < 4; ++is) {
          bfrag bb = *(const bfrag*)&wlt[is * 16 + lr][ks * 32 + lg * 8];
          acc[ts][is] = MFMA(a, bb, acc[ts][is]);
        }
      }
#pragma unroll
    for (int ts = 0; ts < 2; ++ts)
#pragma unroll
      for (int is = 0; is < 4; ++is)
#pragma unroll
        for (int j = 0; j < 4; ++j) {
          int t = r0 + w * 32 + ts * 16 + lg * 4 + j;
          int i2 = is * 16 + lr;
          RWb[((size_t)(b * 1024 + t)) * 64 + i2] = f2b(acc[ts][is][j]);
        }
  }
  {
    // R/P = wgt @ seqs^T : [128 k x 128 r]; wave w owns k in [32w, 32w+32)
    ffrag acc[2][8] = {};
#pragma unroll
    for (int ks = 0; ks < 2; ++ks)
#pragma unroll
      for (int ksb = 0; ksb < 2; ++ksb) {
        bfrag a = *(const bfrag*)&wgt[w * 32 + ksb * 16 + lr][ks * 32 + lg * 8];
#pragma unroll
        for (int ts = 0; ts < 8; ++ts) {
          bfrag bb = *(const bfrag*)&seqs[ts * 16 + lr][ks * 32 + lg * 8];
          acc[ksb][ts] = MFMA(a, bb, acc[ksb][ts]);
        }
      }
    unsigned short* dst = (side == 0) ? Rb : Pb;
#pragma unroll
    for (int ksb = 0; ksb < 2; ++ksb)
#pragma unroll
      for (int ts = 0; ts < 8; ++ts)
#pragma unroll
        for (int j = 0; j < 4; ++j) {
          int k = w * 32 + ksb * 16 + lg * 4 + j;
          int t = r0 + ts * 16 + lr;
          dst[((size_t)(b * 128 + k)) * 1024 + t] = f2b(acc[ksb][ts][j]);
        }
  }
}

// ---------------------------------------------------------------------------
// hz (fused hp+hr): role 0: z_p, resident = post n-strip, chunk over t (RW),
//                   coeff = R, addterm = P.
//                   role 1: z_r, resident = RW t-strip, chunk over n (post),
//                   coeff = P, addterm = R.
// Per block (strip s0 of 128, batch b, role): loop 32 chunks of 32:
//   Ltile[res][chk] = tanh(MFMA(chunk, resident)) -> LDS packed
//   acc[k][res] += coeff[k][chk] @ Ltile          (MFMA)
// epilogue: z[res] = sum_k wh[k] * tanh(acc + addterm[k][res])
// LDS layout (40960 B total = 4 blocks/CU):
//   postl [128][64] bf16 XOR-swizzled (slot^=(row&7))   @0      (16384)
//   rwl   [32][64]  bf16 XOR-swizzled                   @16384  (4096)
//   rl    [128][40] bf16 padded                         @20480  (10240)
//   ll    [128][40] bf16 padded (aliased by zacc[4][128] f32 in epilogue)
//                                                       @30720  (10240)
// ---------------------------------------------------------------------------
__global__ __launch_bounds__(256, 4) void hz_kernel(
    const unsigned short* __restrict__ RWb, const unsigned short* __restrict__ Rb,
    const unsigned short* __restrict__ Pb, const unsigned short* __restrict__ postb,
    const float* __restrict__ whp, const float* __restrict__ whr,
    float* __restrict__ zp, float* __restrict__ zr)
{
  const int s0 = blockIdx.x * 128, b = blockIdx.y, role = blockIdx.z;
  const int tid = threadIdx.x, lane = tid & 63, w = tid >> 6;
  const int lr = lane & 15, lg = lane >> 4;

  const unsigned short* resident = role ? RWb : postb;
  const unsigned short* chunkseq = role ? postb : RWb;
  const unsigned short* coeff    = role ? Pb : Rb;
  const unsigned short* addterm  = role ? Rb : Pb;
  const float* wh                = role ? whr : whp;
  float* zout                    = role ? zr : zp;

  __shared__ __align__(16) char smem[40960];
  char* postl = smem;                 // [128] rows x 128B, swizzled
  char* rwl   = smem + 16384;         // [32] rows x 128B, swizzled
  char* rl    = smem + 20480;         // [128] rows x 80B (40 shorts, 32 used)
  char* ll    = smem + 30720;         // [128] rows x 80B
  float* zacc = (float*)(smem + 30720);  // alias ll (epilogue only)

  // ---- prologue: resident strip (swizzled) ----
  {
    const char* src = (const char*)resident + ((size_t)(b * 1024 + s0)) * 128;
    const int row = tid >> 1, half = tid & 1;
#pragma unroll
    for (int q = 0; q < 4; ++q) {
      int slot = half * 4 + q;
      uint4 v = *(const uint4*)(src + row * 128 + slot * 16);
      *(uint4*)(postl + row * 128 + ((slot ^ (row & 7)) << 4)) = v;
    }
  }
  // ---- prologue: chunk 0 ----
  {
    const char* csrc = (const char*)chunkseq + ((size_t)(b * 1024)) * 128;
    const int r = tid >> 3, slot = tid & 7;
    uint4 v = *(const uint4*)(csrc + r * 128 + slot * 16);
    *(uint4*)(rwl + r * 128 + ((slot ^ (r & 7)) << 4)) = v;
    const char* ksrc = (const char*)coeff + ((size_t)(b * 128)) * 2048;
    const int k0 = tid >> 2, part = tid & 3;
    uint4 v0 = *(const uint4*)(ksrc + (size_t)k0 * 2048 + part * 16);
    uint4 v1 = *(const uint4*)(ksrc + (size_t)(k0 + 64) * 2048 + part * 16);
    *(uint4*)(rl + k0 * 80 + part * 16) = v0;
    *(uint4*)(rl + (k0 + 64) * 80 + part * 16) = v1;
  }
  __syncthreads();

  ffrag acc[2][8] = {};   // [ksub][ressub]: k in [32w,32w+32), res all 128
  uint4 pf_c, pf_k0, pf_k1;
  const int pr = tid >> 3, pslot = tid & 7;       // chunkseq prefetch mapping
  const int pk = tid >> 2, ppart = tid & 3;       // coeff prefetch mapping

  for (int tc = 0; tc < 32; ++tc) {
    // prefetch next chunk into registers (latency hidden under compute)
    if (tc < 31) {
      const char* csrc = (const char*)chunkseq + ((size_t)(b * 1024 + (tc + 1) * 32)) * 128;
      pf_c = *(const uint4*)(csrc + pr * 128 + pslot * 16);
      const char* ksrc = (const char*)coeff + ((size_t)(b * 128)) * 2048 + (tc + 1) * 64;
      pf_k0 = *(const uint4*)(ksrc + (size_t)pk * 2048 + ppart * 16);
      pf_k1 = *(const uint4*)(ksrc + (size_t)(pk + 64) * 2048 + ppart * 16);
    }

    // ---- L tile: Ltile[chk][res] = chunk x resident, wave w: res in [32w,32w+32)
    ffrag la[2][2] = {};
#pragma unroll
    for (int ks = 0; ks < 2; ++ks)
#pragma unroll
      for (int ts = 0; ts < 2; ++ts) {
        const int arow = ts * 16 + lr;
        bfrag a = *(const bfrag*)(rwl + arow * 128 + (((ks * 4 + lg) ^ (arow & 7)) << 4));
#pragma unroll
        for (int ns = 0; ns < 2; ++ns) {
          const int brow = w * 32 + ns * 16 + lr;
          bfrag bb = *(const bfrag*)(postl + brow * 128 + (((ks * 4 + lg) ^ (brow & 7)) << 4));
          la[ts][ns] = MFMA(a, bb, la[ts][ns]);
        }
      }
    // tanh + packed store: D row = chk = ts*16+lg*4+j, col = res = ns*16+lr
#pragma unroll
    for (int ts = 0; ts < 2; ++ts)
#pragma unroll
      for (int ns = 0; ns < 2; ++ns) {
        const int res = w * 32 + ns * 16 + lr;
        unsigned p0 = ((unsigned)f2b(ftanh(la[ts][ns][1])) << 16) | f2b(ftanh(la[ts][ns][0]));
        unsigned p1 = ((unsigned)f2b(ftanh(la[ts][ns][3])) << 16) | f2b(ftanh(la[ts][ns][2]));
        uint2 pkv; pkv.x = p0; pkv.y = p1;
        *(uint2*)(ll + res * 80 + ts * 32 + lg * 8) = pkv;   // 8B aligned
      }
    __syncthreads();   // B2: ll visible to all waves

    // ---- GEMM: acc[k][res] += coeff[k][chk] * Ltile (K = 32)
#pragma unroll
    for (int ksb = 0; ksb < 2; ++ksb) {
      bfrag a = *(const bfrag*)(rl + (w * 32 + ksb * 16 + lr) * 80 + lg * 16);
#pragma unroll
      for (int ns = 0; ns < 8; ++ns) {
        bfrag bb = *(const bfrag*)(ll + (ns * 16 + lr) * 80 + lg * 16);
        acc[ksb][ns] = MFMA(a, bb, acc[ksb][ns]);
      }
    }
    // rwl was last read before B2 -> safe to overwrite here
    if (tc < 31)
      *(uint4*)(rwl + pr * 128 + ((pslot ^ (pr & 7)) << 4)) = pf_c;
    __syncthreads();   // B3: GEMM reads of rl/ll done; rwl writes visible
    if (tc < 31) {
      *(uint4*)(rl + pk * 80 + ppart * 16) = pf_k0;
      *(uint4*)(rl + (pk + 64) * 80 + ppart * 16) = pf_k1;
    }
  }

  // ---- epilogue: z[res] = sum_k wh[k] * tanh(acc + addterm)
  float zpart[8] = {0, 0, 0, 0, 0, 0, 0, 0};
#pragma unroll
  for (int ksb = 0; ksb < 2; ++ksb)
#pragma unroll
    for (int j = 0; j < 4; ++j) {
      const int k = w * 32 + ksb * 16 + lg * 4 + j;
      const float whk = wh[k];
      const unsigned short* arow = addterm + ((size_t)(b * 128 + k)) * 1024 + s0;
#pragma unroll
      for (int ns = 0; ns < 8; ++ns) {
        const int res = ns * 16 + lr;
        float h = ftanh(acc[ksb][ns][j] + b2f(arow[res]));
        zpart[ns] += whk * h;
      }
    }
#pragma unroll
  for (int ns = 0; ns < 8; ++ns) {
    zpart[ns] += __shfl_xor(zpart[ns], 16);
    zpart[ns] += __shfl_xor(zpart[ns], 32);
  }
  if (lg == 0) {
#pragma unroll
    for (int ns = 0; ns < 8; ++ns) zacc[w * 128 + ns * 16 + lr] = zpart[ns];
  }
  __syncthreads();
  if (tid < 128)
    zout[(size_t)b * 1024 + s0 + tid] =
        zacc[tid] + zacc[128 + tid] + zacc[256 + tid] + zacc[384 + tid];
}

// ---------------------------------------------------------------------------
// final: per b: softmax(z) -> weighted sum of f32 sequences -> out [B,128]
// ---------------------------------------------------------------------------
__global__ __launch_bounds__(256) void final_kernel(
    const float* __restrict__ review, const float* __restrict__ post,
    const float* __restrict__ zp, const float* __restrict__ zr,
    float* __restrict__ out)
{
  const int b = blockIdx.x, tid = threadIdx.x;
  __shared__ float zl[1024];
  __shared__ float red[256];
  __shared__ float cacc[4][64];

  for (int side = 0; side < 2; ++side) {
    const float* z = (side == 0) ? zp : zr;
    const float* seq = (side == 0) ? post : review;
    for (int i = tid; i < 1024; i += 256) zl[i] = z[(size_t)b * 1024 + i];
    __syncthreads();
    float m = -3.4e38f;
    for (int i = tid; i < 1024; i += 256) m = fmaxf(m, zl[i]);
    red[tid] = m;
    __syncthreads();
    for (int s = 128; s > 0; s >>= 1) {
      if (tid < s) red[tid] = fmaxf(red[tid], red[tid + s]);
      __syncthreads();
    }
    m = red[0];
    __syncthreads();
    float sm = 0.f;
    for (int i = tid; i < 1024; i += 256) {
      float e = __expf(zl[i] - m);
      zl[i] = e;
      sm += e;
    }
    red[tid] = sm;
    __syncthreads();
    for (int s = 128; s > 0; s >>= 1) {
      if (tid < s) red[tid] += red[tid + s];
      __syncthreads();
    }
    float inv = 1.0f / red[0];
    __syncthreads();
    const int d = tid & 63, g = tid >> 6;
    float a = 0.f;
    for (int n = g * 256; n < g * 256 + 256; ++n)
      a += zl[n] * seq[((size_t)(b * 1024 + n)) * 64 + d];
    cacc[g][d] = a * inv;
    __syncthreads();
    if (tid < 64)
      out[b * 128 + side * 64 + tid] =
          cacc[0][tid] + cacc[1][tid] + cacc[2][tid] + cacc[3][tid];
    __syncthreads();
  }
}

// ---------------------------------------------------------------------------
extern "C" void kernel_launch(void* const* d_in, const int* in_sizes, int n_in,
                              void* d_out, int out_size, void* d_ws, size_t ws_size,
                              hipStream_t stream) {
  const float* review = (const float*)d_in[0];
  const float* post   = (const float*)d_in[1];
  const float* Wl     = (const float*)d_in[2];
  const float* Wr     = (const float*)d_in[3];
  const float* Wp     = (const float*)d_in[4];
  const float* whr    = (const float*)d_in[5];
  const float* whp    = (const float*)d_in[6];
  float* out = (float*)d_out;

  char* ws = (char*)d_ws;
  // Workspace layout (48.5 MB total):
  unsigned short* RWb   = (unsigned short*)(ws);                        //  8 MiB
  unsigned short* Rb    = (unsigned short*)(ws + (size_t)8  * 1048576); // 16 MiB
  unsigned short* Pb    = (unsigned short*)(ws + (size_t)24 * 1048576); // 16 MiB
  unsigned short* postb = (unsigned short*)(ws + (size_t)40 * 1048576); //  8 MiB
  float* zp = (float*)(ws + (size_t)48 * 1048576);                      // 256 KiB
  float* zr = (float*)(ws + (size_t)48 * 1048576 + 262144);             // 256 KiB

  prep_kernel<<<dim3(8, 64, 2), dim3(256), 0, stream>>>(
      review, post, Wl, Wr, Wp, RWb, Rb, Pb, postb);
  hz_kernel<<<dim3(8, 64, 2), dim3(256), 0, stream>>>(
      RWb, Rb, Pb, postb, whp, whr, zp, zr);
  final_kernel<<<dim3(64), dim3(256), 0, stream>>>(
      review, post, zp, zr, out);
}

// Round 3
// 108.703 us; speedup vs baseline: 2.3683x; 1.1899x over previous
//
#include <hip/hip_runtime.h>
#include <hip/hip_bf16.h>

// Problem constants: B=64, T=N=1024, d=64, k=128.

typedef __attribute__((ext_vector_type(8))) short bfrag;   // 8 x bf16 (4 VGPRs)
typedef __attribute__((ext_vector_type(4))) float ffrag;   // 4 x f32 acc

__device__ __forceinline__ unsigned short f2b(float f) {
  unsigned u = __builtin_bit_cast(unsigned, f);
  u += 0x7FFFu + ((u >> 16) & 1u);          // RNE f32 -> bf16 (finite inputs)
  return (unsigned short)(u >> 16);
}
__device__ __forceinline__ float b2f(unsigned short h) {
  return __builtin_bit_cast(float, (unsigned)h << 16);
}
__device__ __forceinline__ float ftanh(float x) {
  // tanh(x) = 1 - 2/(2^(x*2*log2e)+1); ~1e-6 abs err
  float e = __builtin_amdgcn_exp2f(x * 2.88539008177792681f);
  return fmaf(-2.0f, __builtin_amdgcn_rcpf(e + 1.0f), 1.0f);
}
// pack two f32 -> packed bf16 pair {lo, hi}; round-half-up (+0x8000), then
// one v_perm_b32 grabs the two high halves. Ties differ from RNE only on
// exact .5 ulp values (measure-zero for random data).
__device__ __forceinline__ unsigned pack2(float lo, float hi) {
  unsigned a = __builtin_bit_cast(unsigned, lo) + 0x8000u;
  unsigned b = __builtin_bit_cast(unsigned, hi) + 0x8000u;
  return __builtin_amdgcn_perm(b, a, 0x07060302u);
}

#define MFMA(a, b, c) __builtin_amdgcn_mfma_f32_16x16x32_bf16((a), (b), (c), 0, 0, 0)

// ---------------------------------------------------------------------------
// prep: RWb = bf16(review@Wl)  [B,T,64]
//       Rb  = bf16(Wr@review^T) stored [B,128,T]
//       Pb  = bf16(Wp@post^T)   stored [B,128,N]
//       postb = bf16(post)      [B,N,64]
// grid (8 chunks, 64 b, 2 sides), 256 threads
// ---------------------------------------------------------------------------
__global__ __launch_bounds__(256) void prep_kernel(
    const float* __restrict__ review, const float* __restrict__ post,
    const float* __restrict__ Wl, const float* __restrict__ Wr,
    const float* __restrict__ Wp,
    unsigned short* __restrict__ RWb, unsigned short* __restrict__ Rb,
    unsigned short* __restrict__ Pb, unsigned short* __restrict__ postb)
{
  const int chunk = blockIdx.x, b = blockIdx.y, side = blockIdx.z;
  const int tid = threadIdx.x, lane = tid & 63, w = tid >> 6;
  const int lr = lane & 15, lg = lane >> 4;
  const int r0 = chunk * 128;

  __shared__ __align__(16) unsigned short seqs[128][72];  // seq rows [r][d]
  __shared__ __align__(16) unsigned short wgt[128][72];   // Wr or Wp [k][d]
  __shared__ __align__(16) unsigned short wlt[64][72];    // Wl^T [i][d]

  const float* seq = (side == 0) ? review : post;
  for (int i = tid; i < 128 * 64; i += 256) {
    int r = i >> 6, d = i & 63;
    unsigned short h = f2b(seq[((size_t)(b * 1024 + r0 + r)) * 64 + d]);
    seqs[r][d] = h;
    if (side == 1) postb[((size_t)(b * 1024 + r0 + r)) * 64 + d] = h;
  }
  const float* wkd = (side == 0) ? Wr : Wp;
  for (int i = tid; i < 128 * 64; i += 256) {
    int k = i >> 6, d = i & 63;
    wgt[k][d] = f2b(wkd[k * 64 + d]);
  }
  if (side == 0) {
    for (int i = tid; i < 64 * 64; i += 256) {
      int d = i >> 6, c = i & 63;
      wlt[c][d] = f2b(Wl[d * 64 + c]);
    }
  }
  __syncthreads();

  if (side == 0) {
    // RW = seqs @ Wl : [128 x 64]; wave w owns t in [32w, 32w+32)
    ffrag acc[2][4] = {};
#pragma unroll
    for (int ks = 0; ks < 2; ++ks)
#pragma unroll
      for (int ts = 0; ts < 2; ++ts) {
        bfrag a = *(const bfrag*)&seqs[w * 32 + ts * 16 + lr][ks * 32 + lg * 8];
#pragma unroll
        for (int is = 0; is < 4; ++is) {
          bfrag bb = *(const bfrag*)&wlt[is * 16 + lr][ks * 32 + lg * 8];
          acc[ts][is] = MFMA(a, bb, acc[ts][is]);
        }
      }
#pragma unroll
    for (int ts = 0; ts < 2; ++ts)
#pragma unroll
      for (int is = 0; is < 4; ++is)
#pragma unroll
        for (int j = 0; j < 4; ++j) {
          int t = r0 + w * 32 + ts * 16 + lg * 4 + j;
          int i2 = is * 16 + lr;
          RWb[((size_t)(b * 1024 + t)) * 64 + i2] = f2b(acc[ts][is][j]);
        }
  }
  {
    // R/P = wgt @ seqs^T : [128 k x 128 r]; wave w owns k in [32w, 32w+32)
    ffrag acc[2][8] = {};
#pragma unroll
    for (int ks = 0; ks < 2; ++ks)
#pragma unroll
      for (int ksb = 0; ksb < 2; ++ksb) {
        bfrag a = *(const bfrag*)&wgt[w * 32 + ksb * 16 + lr][ks * 32 + lg * 8];
#pragma unroll
        for (int ts = 0; ts < 8; ++ts) {
          bfrag bb = *(const bfrag*)&seqs[ts * 16 + lr][ks * 32 + lg * 8];
          acc[ksb][ts] = MFMA(a, bb, acc[ksb][ts]);
        }
      }
    unsigned short* dst = (side == 0) ? Rb : Pb;
#pragma unroll
    for (int ksb = 0; ksb < 2; ++ksb)
#pragma unroll
      for (int ts = 0; ts < 8; ++ts)
#pragma unroll
        for (int j = 0; j < 4; ++j) {
          int k = w * 32 + ksb * 16 + lg * 4 + j;
          int t = r0 + ts * 16 + lr;
          dst[((size_t)(b * 128 + k)) * 1024 + t] = f2b(acc[ksb][ts][j]);
        }
  }
}

// ---------------------------------------------------------------------------
// hz (fused hp+hr): role 0: z_p; role 1: z_r (symmetric swap).
// 1-D grid 1024; XCD-chunked swizzle: XCD x owns logical [x*128, x*128+128)
// = 16 (b,role) pairs x 8 strips, strips launch-adjacent -> L2 reuse of
// coeff (256KB) + chunkseq (128KB) per pair.
// LDS (36864 B, 4 blocks/CU):
//   postl @0     [128 rows][128B] XOR-swizzled bf16 resident strip
//   rwl   @16384 [32 rows][128B]  XOR-swizzled bf16 chunk
//   rl    @20480 [4 slots][128 k][16B] fragment-major coeff chunk
//   ll    @28672 [4 slots][128 res][16B] fragment-major L tile (zacc alias)
// ---------------------------------------------------------------------------
__global__ __launch_bounds__(256, 4) void hz_kernel(
    const unsigned short* __restrict__ RWb, const unsigned short* __restrict__ Rb,
    const unsigned short* __restrict__ Pb, const unsigned short* __restrict__ postb,
    const float* __restrict__ whp, const float* __restrict__ whr,
    float* __restrict__ zp, float* __restrict__ zr)
{
  const int orig = blockIdx.x;
  const int swz = (orig & 7) * 128 + (orig >> 3);   // XCD-chunked, bijective
  const int strip = swz & 7, pair = swz >> 3;
  const int b = pair & 63, role = pair >> 6;
  const int s0 = strip * 128;
  const int tid = threadIdx.x, lane = tid & 63, w = tid >> 6;
  const int lr = lane & 15, lg = lane >> 4;

  const unsigned short* resident = role ? RWb : postb;
  const unsigned short* chunkseq = role ? postb : RWb;
  const unsigned short* coeff    = role ? Pb : Rb;
  const unsigned short* addterm  = role ? Rb : Pb;
  const float* wh                = role ? whr : whp;
  float* zout                    = role ? zr : zp;

  __shared__ __align__(16) char smem[36864];
  char* postl = smem;                    // swizzled rows of 128B
  char* rwl   = smem + 16384;            // swizzled rows of 128B
  char* rl    = smem + 20480;            // [slot][k][16B]
  char* ll    = smem + 28672;            // [slot][res][16B]
  float* zacc = (float*)(smem + 28672);  // alias ll (epilogue only)

  // ---- prologue: resident strip (swizzled rows) ----
  {
    const char* src = (const char*)resident + ((size_t)(b * 1024 + s0)) * 128;
    const int row = tid >> 1, half = tid & 1;
#pragma unroll
    for (int q = 0; q < 4; ++q) {
      int slot = half * 4 + q;
      uint4 v = *(const uint4*)(src + row * 128 + slot * 16);
      *(uint4*)(postl + row * 128 + ((slot ^ (row & 7)) << 4)) = v;
    }
  }
  // ---- prologue: chunk 0 ----
  {
    const char* csrc = (const char*)chunkseq + ((size_t)(b * 1024)) * 128;
    const int r = tid >> 3, slot = tid & 7;
    uint4 v = *(const uint4*)(csrc + r * 128 + slot * 16);
    *(uint4*)(rwl + r * 128 + ((slot ^ (r & 7)) << 4)) = v;
    const char* ksrc = (const char*)coeff + ((size_t)(b * 128)) * 2048;
    const int k0 = tid >> 2, part = tid & 3;
    uint4 v0 = *(const uint4*)(ksrc + (size_t)k0 * 2048 + part * 16);
    uint4 v1 = *(const uint4*)(ksrc + (size_t)(k0 + 64) * 2048 + part * 16);
    *(uint4*)(rl + part * 2048 + k0 * 16) = v0;
    *(uint4*)(rl + part * 2048 + (k0 + 64) * 16) = v1;
  }
  __syncthreads();

  ffrag acc[2][8] = {};   // [ksub][ressub]: k in [32w,32w+32), res all 128
  uint4 pf_c, pf_k0, pf_k1;
  const int pr = tid >> 3, pslot = tid & 7;       // chunkseq prefetch mapping
  const int pk = tid >> 2, ppart = tid & 3;       // coeff prefetch mapping

  for (int tc = 0; tc < 32; ++tc) {
    // prefetch next chunk into registers (latency hidden under compute)
    if (tc < 31) {
      const char* csrc = (const char*)chunkseq + ((size_t)(b * 1024 + (tc + 1) * 32)) * 128;
      pf_c = *(const uint4*)(csrc + pr * 128 + pslot * 16);
      const char* ksrc = (const char*)coeff + ((size_t)(b * 128)) * 2048 + (tc + 1) * 64;
      pf_k0 = *(const uint4*)(ksrc + (size_t)pk * 2048 + ppart * 16);
      pf_k1 = *(const uint4*)(ksrc + (size_t)(pk + 64) * 2048 + ppart * 16);
    }

    // ---- L tile: Ltile[chk][res], wave w: res in [32w,32w+32)
    ffrag la[2][2] = {};
#pragma unroll
    for (int ks = 0; ks < 2; ++ks)
#pragma unroll
      for (int ts = 0; ts < 2; ++ts) {
        const int arow = ts * 16 + lr;
        bfrag a = *(const bfrag*)(rwl + arow * 128 + (((ks * 4 + lg) ^ (arow & 7)) << 4));
#pragma unroll
        for (int ns = 0; ns < 2; ++ns) {
          const int brow = w * 32 + ns * 16 + lr;
          bfrag bb = *(const bfrag*)(postl + brow * 128 + (((ks * 4 + lg) ^ (brow & 7)) << 4));
          la[ts][ns] = MFMA(a, bb, la[ts][ns]);
        }
      }
    // tanh + pack + fragment-major store:
    // chunk col c = ts*16+lg*4+j -> slot = ts*2+(lg>>1), byte = (lg&1)*8+j*2
#pragma unroll
    for (int ts = 0; ts < 2; ++ts)
#pragma unroll
      for (int ns = 0; ns < 2; ++ns) {
        const int res = w * 32 + ns * 16 + lr;
        uint2 pkv;
        pkv.x = pack2(ftanh(la[ts][ns][0]), ftanh(la[ts][ns][1]));
        pkv.y = pack2(ftanh(la[ts][ns][2]), ftanh(la[ts][ns][3]));
        *(uint2*)(ll + (ts * 2 + (lg >> 1)) * 2048 + res * 16 + (lg & 1) * 8) = pkv;
      }
    __syncthreads();   // B2: ll visible to all waves

    // ---- GEMM: acc[k][res] += coeff[k][chk] * Ltile (K = 32)
    bfrag bbr[8];
#pragma unroll
    for (int ns = 0; ns < 8; ++ns)
      bbr[ns] = *(const bfrag*)(ll + lg * 2048 + (ns * 16 + lr) * 16);
#pragma unroll
    for (int ksb = 0; ksb < 2; ++ksb) {
      bfrag a = *(const bfrag*)(rl + lg * 2048 + (w * 32 + ksb * 16 + lr) * 16);
#pragma unroll
      for (int ns = 0; ns < 8; ++ns)
        acc[ksb][ns] = MFMA(a, bbr[ns], acc[ksb][ns]);
    }
    // rwl last read before B2 -> safe to overwrite now
    if (tc < 31)
      *(uint4*)(rwl + pr * 128 + ((pslot ^ (pr & 7)) << 4)) = pf_c;
    __syncthreads();   // B3: GEMM reads of rl/ll done; rwl writes visible
    if (tc < 31) {
      *(uint4*)(rl + ppart * 2048 + pk * 16) = pf_k0;
      *(uint4*)(rl + ppart * 2048 + (pk + 64) * 16) = pf_k1;
    }
  }

  // ---- epilogue: z[res] = sum_k wh[k] * tanh(acc + addterm)
  float zpart[8] = {0, 0, 0, 0, 0, 0, 0, 0};
#pragma unroll
  for (int ksb = 0; ksb < 2; ++ksb)
#pragma unroll
    for (int j = 0; j < 4; ++j) {
      const int k = w * 32 + ksb * 16 + lg * 4 + j;
      const float whk = wh[k];
      const unsigned short* arow = addterm + ((size_t)(b * 128 + k)) * 1024 + s0;
#pragma unroll
      for (int ns = 0; ns < 8; ++ns) {
        const int res = ns * 16 + lr;
        float h = ftanh(acc[ksb][ns][j] + b2f(arow[res]));
        zpart[ns] += whk * h;
      }
    }
#pragma unroll
  for (int ns = 0; ns < 8; ++ns) {
    zpart[ns] += __shfl_xor(zpart[ns], 16);
    zpart[ns] += __shfl_xor(zpart[ns], 32);
  }
  if (lg == 0) {
#pragma unroll
    for (int ns = 0; ns < 8; ++ns) zacc[w * 128 + ns * 16 + lr] = zpart[ns];
  }
  __syncthreads();
  if (tid < 128)
    zout[(size_t)b * 1024 + s0 + tid] =
        zacc[tid] + zacc[128 + tid] + zacc[256 + tid] + zacc[384 + tid];
}

// ---------------------------------------------------------------------------
// final: block (b, side): softmax(z) -> weighted sum of f32 seq -> out[b,side]
// ---------------------------------------------------------------------------
__global__ __launch_bounds__(256) void final_kernel(
    const float* __restrict__ review, const float* __restrict__ post,
    const float* __restrict__ zp, const float* __restrict__ zr,
    float* __restrict__ out)
{
  const int b = blockIdx.x, side = blockIdx.y, tid = threadIdx.x;
  __shared__ float zl[1024];
  __shared__ float red[256];
  __shared__ float cacc[4][64];

  const float* z = (side == 0) ? zp : zr;
  const float* seq = (side == 0) ? post : review;
  for (int i = tid; i < 1024; i += 256) zl[i] = z[(size_t)b * 1024 + i];
  __syncthreads();
  float m = -3.4e38f;
  for (int i = tid; i < 1024; i += 256) m = fmaxf(m, zl[i]);
  red[tid] = m;
  __syncthreads();
  for (int s = 128; s > 0; s >>= 1) {
    if (tid < s) red[tid] = fmaxf(red[tid], red[tid + s]);
    __syncthreads();
  }
  m = red[0];
  __syncthreads();
  float sm = 0.f;
  for (int i = tid; i < 1024; i += 256) {
    float e = __expf(zl[i] - m);
    zl[i] = e;
    sm += e;
  }
  red[tid] = sm;
  __syncthreads();
  for (int s = 128; s > 0; s >>= 1) {
    if (tid < s) red[tid] += red[tid + s];
    __syncthreads();
  }
  float inv = 1.0f / red[0];
  __syncthreads();
  const int d = tid & 63, g = tid >> 6;
  float a = 0.f;
  for (int n = g * 256; n < g * 256 + 256; ++n)
    a += zl[n] * seq[((size_t)(b * 1024 + n)) * 64 + d];
  cacc[g][d] = a * inv;
  __syncthreads();
  if (tid < 64)
    out[b * 128 + side * 64 + tid] =
        cacc[0][tid] + cacc[1][tid] + cacc[2][tid] + cacc[3][tid];
}

// ---------------------------------------------------------------------------
extern "C" void kernel_launch(void* const* d_in, const int* in_sizes, int n_in,
                              void* d_out, int out_size, void* d_ws, size_t ws_size,
                              hipStream_t stream) {
  const float* review = (const float*)d_in[0];
  const float* post   = (const float*)d_in[1];
  const float* Wl     = (const float*)d_in[2];
  const float* Wr     = (const float*)d_in[3];
  const float* Wp     = (const float*)d_in[4];
  const float* whr    = (const float*)d_in[5];
  const float* whp    = (const float*)d_in[6];
  float* out = (float*)d_out;

  char* ws = (char*)d_ws;
  unsigned short* RWb   = (unsigned short*)(ws);                        //  8 MiB
  unsigned short* Rb    = (unsigned short*)(ws + (size_t)8  * 1048576); // 16 MiB
  unsigned short* Pb    = (unsigned short*)(ws + (size_t)24 * 1048576); // 16 MiB
  unsigned short* postb = (unsigned short*)(ws + (size_t)40 * 1048576); //  8 MiB
  float* zp = (float*)(ws + (size_t)48 * 1048576);                      // 256 KiB
  float* zr = (float*)(ws + (size_t)48 * 1048576 + 262144);             // 256 KiB

  prep_kernel<<<dim3(8, 64, 2), dim3(256), 0, stream>>>(
      review, post, Wl, Wr, Wp, RWb, Rb, Pb, postb);
  hz_kernel<<<dim3(1024), dim3(256), 0, stream>>>(
      RWb, Rb, Pb, postb, whp, whr, zp, zr);
  final_kernel<<<dim3(64, 2), dim3(256), 0, stream>>>(
      review, post, zp, zr, out);
}